// Round 7
// baseline (246.017 us; speedup 1.0000x reference)
//
#include <hip/hip_runtime.h>
#include <math.h>

#define B     4096
#define ND    13
#define NS    26
#define NF    39
#define VOCAB 100000
#define NP    351      // l<=m pairs in 26x26
#define NPP   360      // padded to 8 chunks * 45
#define CHP   45       // p's per chunk
#define GSTR  28       // Gst row: [0..25]=Gs_j, [26]=A1s, [27]=lut bits

// ---------------- workspace layout (floats) ----------------
#define OFF_GST  0         // 360*28 = 10080
#define OFF_CST  10080     // 1
#define OFF_C2J  10088     // 26
#define OFF_LIN  10240     // 4096
#define OFF_SCIN 14336     // 4096
#define OFF_H0   18432     // 4096*224 = 917504
#define OFF_H1   935936    // 4096*256 = 1048576  (ends 1984512 fl ~ 7.9 MB)

// ---- precompute: Gst (transposed, padded), cst, c2j ----
__global__ __launch_bounds__(256) void k_pre(const float* __restrict__ W0,
                                             const float* __restrict__ W1,
                                             const float* __restrict__ b0,
                                             const float* __restrict__ b1,
                                             const float* __restrict__ clw,
                                             float* __restrict__ Gst,
                                             float* __restrict__ cst,
                                             float* __restrict__ c2j) {
    int blk = blockIdx.x, tid = threadIdx.x;
    if (blk < 26) {
        int j = blk;
        __shared__ float vh[2][128];
        __shared__ float vj[128];
        __shared__ float c2r[2];
        {
            int i = tid & 127, h = tid >> 7;
            const float* wp = W1 + (long)(h * 64) * 3328 + i * 26 + j;
            float acc = 0.f;
#pragma unroll 8
            for (int o = 0; o < 64; o++) acc += clw[128 + h * 64 + o] * wp[o * 3328];
            vh[h][i] = acc;
        }
        __syncthreads();
        if (tid < 128) {
            float vv = vh[0][tid] + vh[1][tid];
            vj[tid] = vv;
            float c = vv * b0[tid];
            for (int off = 32; off; off >>= 1) c += __shfl_down(c, off, 64);
            if ((tid & 63) == 0) c2r[tid >> 6] = c;
        }
        __syncthreads();
        if (tid == 0) c2j[j] = c2r[0] + c2r[1];
        for (int p = tid; p < NPP; p += 256) {
            float g = 0.f;
            if (p < NP) {
                int l = 0, rem = p;
                while (rem >= NS - l) { rem -= NS - l; l++; }
                int m = l + rem;
                float sym = (l != m) ? 1.f : 0.f;
                const float* wa = W0 + l * 26 + m;
                const float* wb = W0 + m * 26 + l;
#pragma unroll 8
                for (int i = 0; i < 128; i++)
                    g += vj[i] * (wa[i * 676] + sym * wb[i * 676]);
            }
            Gst[p * GSTR + j] = g;
        }
    } else if (blk == 26) {
        for (int p = tid; p < NPP; p += 256) {
            float a = 0.f; int lmbits = 0;
            if (p < NP) {
                int l = 0, rem = p;
                while (rem >= NS - l) { rem -= NS - l; l++; }
                int m = l + rem;
                float sym = (l != m) ? 1.f : 0.f;
                const float* wa = W0 + l * 26 + m;
                const float* wb = W0 + m * 26 + l;
#pragma unroll 8
                for (int o = 0; o < 128; o++)
                    a += clw[o] * (wa[o * 676] + sym * wb[o * 676]);
                lmbits = (l << 5) | m;
            }
            Gst[p * GSTR + 26] = a;
            Gst[p * GSTR + 27] = __int_as_float(lmbits);
        }
    } else {
        __shared__ float red[2];
        float c = 0.f;
        if (tid < 128) {
            c = clw[tid] * b0[tid] + clw[128 + tid] * b1[tid];
            for (int off = 32; off; off >>= 1) c += __shfl_down(c, off, 64);
            if ((tid & 63) == 0) red[tid >> 6] = c;
        }
        __syncthreads();
        if (tid == 0) cst[0] = 8.f * (red[0] + red[1]);
    }
}

// ---- per-row kernel: gather + linear + CIN. One wave per row, grid = 4096. ----
__global__ __launch_bounds__(64, 4) void k_rows(
    const float* __restrict__ inputs, const float* __restrict__ tables,
    const float* __restrict__ lW, const float* __restrict__ lb,
    const float* __restrict__ Gst, const float* __restrict__ c2j,
    const float* __restrict__ cst,
    float* __restrict__ h0, float* __restrict__ lin, float* __restrict__ scin) {
    __shared__ float insf[40];
    __shared__ float xs[208];
    int b = blockIdx.x, lane = threadIdx.x;

    if (lane < NF) insf[lane] = inputs[b * NF + lane];
    __syncthreads();
    // gather: 52 lanes, one float4 each
    if (lane < 52) {
        int f = lane >> 1, h = lane & 1;
        int idx = (int)insf[ND + f];
        float4 v = *(const float4*)(tables + ((long)f * VOCAB + idx) * 8 + h * 4);
        *(float4*)&xs[f * 8 + h * 4] = v;
    }
    __syncthreads();
    // h0 row (padded 224) + linear term
    for (int t = lane; t < 224; t += 64) {
        float v = (t < ND) ? insf[t] : ((t < 221) ? xs[t - 13] : 0.f);
        h0[(long)b * 224 + t] = v;
    }
    {
        float p = (lane < NF) ? insf[lane] * lW[lane] : 0.f;
#pragma unroll
        for (int off = 1; off < 64; off <<= 1) p += __shfl_xor(p, off, 64);
        if (lane == 0) lin[b] = p + lb[0];
    }
    // CIN: lane = (chunk c in 0..7) * 8 + k
    {
        int k = lane & 7, c = lane >> 3;
        const float* gr = Gst + c * (CHP * GSTR);
        float t[27];
#pragma unroll
        for (int j = 0; j < 27; j++) t[j] = 0.f;
        for (int pi = 0; pi < CHP; pi++) {
            const float4* g4 = (const float4*)(gr + pi * GSTR);
            float4 g6 = g4[6];
            int lm = __float_as_int(g6.w);
            float q = xs[(lm >> 5) * 8 + k] * xs[(lm & 31) * 8 + k];
            float4 g0 = g4[0], g1 = g4[1], g2 = g4[2];
            float4 g3 = g4[3], g4v = g4[4], g5 = g4[5];
            t[0]  += g0.x * q; t[1]  += g0.y * q; t[2]  += g0.z * q; t[3]  += g0.w * q;
            t[4]  += g1.x * q; t[5]  += g1.y * q; t[6]  += g1.z * q; t[7]  += g1.w * q;
            t[8]  += g2.x * q; t[9]  += g2.y * q; t[10] += g2.z * q; t[11] += g2.w * q;
            t[12] += g3.x * q; t[13] += g3.y * q; t[14] += g3.z * q; t[15] += g3.w * q;
            t[16] += g4v.x * q; t[17] += g4v.y * q; t[18] += g4v.z * q; t[19] += g4v.w * q;
            t[20] += g5.x * q; t[21] += g5.y * q; t[22] += g5.z * q; t[23] += g5.w * q;
            t[24] += g6.x * q; t[25] += g6.y * q; t[26] += g6.z * q;
        }
        float csel = (c == 0) ? 1.f : 0.f;
        float part = t[26];
#pragma unroll
        for (int j = 0; j < 26; j++)
            part += (t[j] + csel * c2j[j]) * xs[j * 8 + k];
#pragma unroll
        for (int off = 1; off < 64; off <<= 1) part += __shfl_xor(part, off, 64);
        if (lane == 0) scin[b] = part + cst[0];
    }
}

// ---- DNN layer1 GEMM: [4096 x 221] @ [221 x 256]. 16 rows x 64 outs per block. ----
#define ITS 20   // inT r-stride (b128-aligned, bank-spread)
__global__ __launch_bounds__(256, 4) void k_dnn1(
    const float* __restrict__ h0,
    const float* __restrict__ dW1, const float* __restrict__ db1,
    float* __restrict__ h1) {
    __shared__ float inT[224 * ITS];       // 17.9 KB, [c][r] stride 20
    __shared__ float psum[64 * 64];        // 16 KB, [ks*16 + r][o64]
    int tid = threadIdx.x;
    int m16 = (blockIdx.x >> 2) * 16;
    int ny = blockIdx.x & 3;

    // stage h0 tile transposed
    for (int t = tid; t < 56 * 16; t += 256) {
        int r = t & 15, c4 = t >> 4;
        float4 v = *(const float4*)&h0[(long)(m16 + r) * 224 + c4 * 4];
        inT[(c4 * 4 + 0) * ITS + r] = v.x;
        inT[(c4 * 4 + 1) * ITS + r] = v.y;
        inT[(c4 * 4 + 2) * ITS + r] = v.z;
        inT[(c4 * 4 + 3) * ITS + r] = v.w;
    }
    __syncthreads();

    int o = tid & 63, ks = tid >> 6;      // ks wave-uniform
    int og = ny * 64 + o;
    float a[16];
#pragma unroll
    for (int i = 0; i < 16; i++) a[i] = 0.f;
    int c0 = ks * 56, c1 = c0 + 56;
    if (c1 > 221) c1 = 221;
    for (int c = c0; c < c1; c++) {
        float w = dW1[c * 256 + og];
        const float* ir = &inT[c * ITS];
        float4 r0 = *(const float4*)(ir + 0);
        float4 r1 = *(const float4*)(ir + 4);
        float4 r2 = *(const float4*)(ir + 8);
        float4 r3 = *(const float4*)(ir + 12);
        a[0] += r0.x * w; a[1] += r0.y * w; a[2]  += r0.z * w; a[3]  += r0.w * w;
        a[4] += r1.x * w; a[5] += r1.y * w; a[6]  += r1.z * w; a[7]  += r1.w * w;
        a[8] += r2.x * w; a[9] += r2.y * w; a[10] += r2.z * w; a[11] += r2.w * w;
        a[12] += r3.x * w; a[13] += r3.y * w; a[14] += r3.z * w; a[15] += r3.w * w;
    }
#pragma unroll
    for (int r = 0; r < 16; r++) psum[(ks * 16 + r) * 64 + o] = a[r];
    __syncthreads();

    for (int t = tid; t < 1024; t += 256) {
        int oi = t & 63, r = t >> 6;
        float s = psum[(0 * 16 + r) * 64 + oi] + psum[(1 * 16 + r) * 64 + oi]
                + psum[(2 * 16 + r) * 64 + oi] + psum[(3 * 16 + r) * 64 + oi];
        s = fmaxf(s + db1[ny * 64 + oi], 0.f);
        h1[(long)(m16 + r) * 256 + ny * 64 + oi] = s;
    }
}

// ---- DNN layers 2-4 + combine + sigmoid. 4 rows per block, grid 1024. ----
__global__ __launch_bounds__(256, 4) void k_dnnrest(
    const float* __restrict__ h1,
    const float* __restrict__ dW2, const float* __restrict__ db2,
    const float* __restrict__ dW3, const float* __restrict__ db3,
    const float* __restrict__ dW4, const float* __restrict__ db4,
    const float* __restrict__ lin, const float* __restrict__ scin,
    const float* __restrict__ clb,
    float* __restrict__ out) {
    __shared__ float h1T[256 * 4];
    __shared__ float ps[512 * 4];
    __shared__ float h2T[128 * 4];
    __shared__ float h3T[64 * 4];
    int tid = threadIdx.x;
    int b4 = blockIdx.x * 4;

    for (int t = tid; t < 1024; t += 256) {
        int c = t & 255, r = t >> 8;
        h1T[c * 4 + r] = h1[(long)(b4 + r) * 256 + c];
    }
    __syncthreads();
    // layer2: 256 -> 128, split-K x2
    {
        int o = tid & 127, ks = tid >> 7;
        float a0 = 0.f, a1 = 0.f, a2 = 0.f, a3 = 0.f;
        for (int c = 0; c < 128; c++) {
            int cc = ks * 128 + c;
            float w = dW2[cc * 128 + o];
            float4 hv = *(const float4*)&h1T[cc * 4];
            a0 += hv.x * w; a1 += hv.y * w; a2 += hv.z * w; a3 += hv.w * w;
        }
        *(float4*)&ps[(ks * 128 + o) * 4] = make_float4(a0, a1, a2, a3);
    }
    __syncthreads();
    if (tid < 128) {
        float4 p0 = *(const float4*)&ps[tid * 4];
        float4 p1 = *(const float4*)&ps[(128 + tid) * 4];
        float bias = db2[tid];
        float4 o0;
        o0.x = fmaxf(p0.x + p1.x + bias, 0.f);
        o0.y = fmaxf(p0.y + p1.y + bias, 0.f);
        o0.z = fmaxf(p0.z + p1.z + bias, 0.f);
        o0.w = fmaxf(p0.w + p1.w + bias, 0.f);
        *(float4*)&h2T[tid * 4] = o0;
    }
    __syncthreads();
    // layer3: 128 -> 64, split-K x4
    {
        int o = tid & 63, ks = tid >> 6;
        float a0 = 0.f, a1 = 0.f, a2 = 0.f, a3 = 0.f;
        for (int c = 0; c < 32; c++) {
            int cc = ks * 32 + c;
            float w = dW3[cc * 64 + o];
            float4 hv = *(const float4*)&h2T[cc * 4];
            a0 += hv.x * w; a1 += hv.y * w; a2 += hv.z * w; a3 += hv.w * w;
        }
        *(float4*)&ps[(ks * 64 + o) * 4] = make_float4(a0, a1, a2, a3);
    }
    __syncthreads();
    if (tid < 64) {
        float s0 = 0.f, s1 = 0.f, s2 = 0.f, s3 = 0.f;
#pragma unroll
        for (int ks = 0; ks < 4; ks++) {
            float4 p = *(const float4*)&ps[(ks * 64 + tid) * 4];
            s0 += p.x; s1 += p.y; s2 += p.z; s3 += p.w;
        }
        float bias = db3[tid];
        float4 o0;
        o0.x = fmaxf(s0 + bias, 0.f); o0.y = fmaxf(s1 + bias, 0.f);
        o0.z = fmaxf(s2 + bias, 0.f); o0.w = fmaxf(s3 + bias, 0.f);
        *(float4*)&h3T[tid * 4] = o0;
    }
    __syncthreads();
    // layer4 + combine (wave 0)
    if (tid < 64) {
        float w4 = dW4[tid];
        float4 h = *(const float4*)&h3T[tid * 4];
        float s0 = h.x * w4, s1 = h.y * w4, s2 = h.z * w4, s3 = h.w * w4;
#pragma unroll
        for (int off = 1; off < 64; off <<= 1) {
            s0 += __shfl_xor(s0, off, 64);
            s1 += __shfl_xor(s1, off, 64);
            s2 += __shfl_xor(s2, off, 64);
            s3 += __shfl_xor(s3, off, 64);
        }
        if (tid == 0) {
            float sv[4] = { s0, s1, s2, s3 };
            float bb = db4[0], cb = clb[0];
#pragma unroll
            for (int r = 0; r < 4; r++) {
                float dense = fmaxf(sv[r] + bb, 0.f);
                float cin = fmaxf(scin[b4 + r] + cb, 0.f);
                float x = lin[b4 + r] + cin + dense;
                out[b4 + r] = 1.f / (1.f + expf(-x));
            }
        }
    }
}

extern "C" void kernel_launch(void* const* d_in, const int* in_sizes, int n_in,
                              void* d_out, int out_size, void* d_ws, size_t ws_size,
                              hipStream_t stream) {
    const float* inputs = (const float*)d_in[0];
    const float* tables = (const float*)d_in[1];
    const float* lW     = (const float*)d_in[2];
    const float* lb     = (const float*)d_in[3];
    const float* W0     = (const float*)d_in[4];
    const float* b0     = (const float*)d_in[5];
    const float* W1c    = (const float*)d_in[6];
    const float* b1c    = (const float*)d_in[7];
    const float* clw    = (const float*)d_in[8];
    const float* clb    = (const float*)d_in[9];
    const float* dW1    = (const float*)d_in[10];
    const float* db1    = (const float*)d_in[11];
    const float* dW2    = (const float*)d_in[12];
    const float* db2    = (const float*)d_in[13];
    const float* dW3    = (const float*)d_in[14];
    const float* db3    = (const float*)d_in[15];
    const float* dW4    = (const float*)d_in[16];
    const float* db4    = (const float*)d_in[17];

    float* ws   = (float*)d_ws;
    float* Gst  = ws + OFF_GST;
    float* cst  = ws + OFF_CST;
    float* c2j  = ws + OFF_C2J;
    float* lin  = ws + OFF_LIN;
    float* scin = ws + OFF_SCIN;
    float* h0   = ws + OFF_H0;
    float* h1   = ws + OFF_H1;

    k_pre<<<28, 256, 0, stream>>>(W0, W1c, b0, b1c, clw, Gst, cst, c2j);
    k_rows<<<B, 64, 0, stream>>>(inputs, tables, lW, lb, Gst, c2j, cst, h0, lin, scin);
    k_dnn1<<<1024, 256, 0, stream>>>(h0, dW1, db1, h1);
    k_dnnrest<<<1024, 256, 0, stream>>>(h1, dW2, db2, dW3, db3, dW4, db4,
                                        lin, scin, clb, (float*)d_out);
}